// Round 7
// baseline (525.422 us; speedup 1.0000x reference)
//
#include <hip/hip_runtime.h>
#include <hip/hip_bf16.h>
#include <math.h>

#define BATCH 512
#define DIM 512
#define NCLASS 100000
#define NCB 3125                     /* class blocks of 32: 100000/32 */
#define BNB 256                      /* tile cols */
#define NT 391                       /* ceil(100000/256) */
#define NSTREAM 64
#define GRID 256                     /* 4 M-groups x 64 streams = 1 block/CU */
#define S_SCALE 30.0f
#define COSM 0.8775825618903728f
#define SINM 0.4794255386042030f
#define LOG2E 1.44269504088896f

typedef unsigned short u16;
typedef __attribute__((ext_vector_type(8))) short short8;
typedef __attribute__((ext_vector_type(4))) float floatx4;
typedef __attribute__((ext_vector_type(16))) float floatx16;

// ws layout (bytes):
//   [0, 524288)            xn bf16 [512][512]     (published by stream-0 blocks)
//   [524288, 655360)       partials [64][512] f32
//   [655360, 657408)       nll float[512]
//   [657408, +102400000)   wn bf16, FRAGMENT-MAJOR:
//     [cblk 0..3124][ks 0..31][lane 0..63][8 bf16]
//     element (class c, k) lives at cblk=c>>5, ks=k>>4,
//     lane=((k>>3)&1)*32 + (c&31), j=k&7  -> matches 32x32x16 MFMA B layout
//     (col=lane&31, k=(lane>>5)*8+j). B loads: base + ks*512 + lane*8 (u16),
//     i.e. 64 lanes x 16B CONTIGUOUS = 1 transaction.

__device__ __forceinline__ u16 f2bf(float f) {
    union { __hip_bfloat16 h; u16 u; } c;
    c.h = __float2bfloat16(f);       // RNE, native v_cvt on gfx950
    return c.u;
}
__device__ __forceinline__ float bf2f(u16 b) {
    union { float f; unsigned int u; } v;
    v.u = ((unsigned int)b) << 16;
    return v.f;
}

// ---------------- Kernel 0: normalize W rows -> fragment-major bf16 wn ----------------
// 3125 blocks x 512 thr; block = one 32-class frag block.
// Phase a: 8 waves x 4 rows -> normalize -> swizzled LDS rows (granule XOR).
// Phase b: coalesced 16B/lane write-out in fragment order (32 KB contiguous).
__global__ void wnorm_kernel(const float* __restrict__ w, u16* __restrict__ wnf) {
    __shared__ __align__(16) u16 rowbuf[32 * 512];   // 32 KB
    const int wv = threadIdx.x >> 6;
    const int l  = threadIdx.x & 63;

    for (int rr = 0; rr < 4; ++rr) {
        const int c = wv * 4 + rr;                   // local class 0..31
        const float* wr = w + (size_t)(blockIdx.x * 32 + c) * DIM;
        const floatx4 a = *(const floatx4*)(wr + 4 * l);
        const floatx4 b = *(const floatx4*)(wr + 256 + 4 * l);
        float ss = a[0]*a[0] + a[1]*a[1] + a[2]*a[2] + a[3]*a[3]
                 + b[0]*b[0] + b[1]*b[1] + b[2]*b[2] + b[3]*b[3];
#pragma unroll
        for (int d = 1; d < 64; d <<= 1) ss += __shfl_xor(ss, d);
        const float rn = 1.0f / fmaxf(sqrtf(ss), 1e-12f);
        ushort4 ua, ub;
        ua.x = f2bf(a[0]*rn); ua.y = f2bf(a[1]*rn); ua.z = f2bf(a[2]*rn); ua.w = f2bf(a[3]*rn);
        ub.x = f2bf(b[0]*rn); ub.y = f2bf(b[1]*rn); ub.z = f2bf(b[2]*rn); ub.w = f2bf(b[3]*rn);
        // lane l holds halves (t&1) of granules (l>>1) and 32+(l>>1); XOR-swizzle granule
        const int g0 = (l >> 1) ^ (c & 7);
        const int g1 = (32 + (l >> 1)) ^ (c & 7);
        *(ushort4*)(&rowbuf[c * 512 + g0 * 8 + (l & 1) * 4]) = ua;
        *(ushort4*)(&rowbuf[c * 512 + g1 * 8 + (l & 1) * 4]) = ub;
    }
    __syncthreads();

    // write-out: thread t, iter i -> out u16 offset i*4096 + t*8 within block
    u16* ob = wnf + (size_t)blockIdx.x * 16384;
    const int t = threadIdx.x;
#pragma unroll
    for (int i = 0; i < 4; ++i) {
        const int ks = i * 8 + (t >> 6);
        const int c31 = t & 31;
        const int hik = (t >> 5) & 1;
        const int g = (ks * 2 + hik) ^ (c31 & 7);    // swizzled source granule
        const short8 v = *(const short8*)(&rowbuf[c31 * 512 + g * 8]);
        *(short8*)(ob + i * 4096 + t * 8) = v;
    }
}

// ---------------- Kernel 1: A-stationary GEMM over fragment-major wn ----------------
// 256 blocks = 4 M-groups (128 rows) x 64 streams; 1 block/CU, 8 waves (g x np).
// A (normalized bf16, XOR-swizzled) pinned in LDS [r5/r6-verified addressing].
// B: coalesced 16B fragment loads straight from wn via 4-deep named pipeline.
// Running exp-sums in LDS pacc. MFMA 32x32x16: C/D col=lane&31,
// row=(reg&3)+8*(reg>>2)+4*(lane>>5)   [m74/m101-verified; r3-r6 correct].
__global__ __launch_bounds__(512, 2) void arcface_main(
        const float* __restrict__ x, const u16* __restrict__ wnf,
        u16* __restrict__ xn, float* __restrict__ partials) {
    __shared__ __align__(16) u16 ash[128 * DIM];   // 128 KB swizzled normalized-A
    __shared__ float pacc[8][64];                  // 2 KB running exp-sums

    const int t = threadIdx.x;
    const int bid = blockIdx.x;
    const int stream = bid & 63;
    const int mgrp = bid >> 6;       // 0..3
    const int wv = t >> 6;
    const int lane = t & 63;
    const int l31 = lane & 31;
    const int hi = lane >> 5;
    const int swz = l31 & 7;
    const int g  = wv >> 2;          // m-half within block (64 rows)
    const int np = wv & 3;           // n-slot (64 classes)

    // ---- prologue: normalize 128 x-rows -> bf16 swizzled LDS (two-pass, no reg tile) ----
    for (int rp = 0; rp < 2; ++rp) {
        const int r = rp * 64 + (t >> 3);
        const int q = t & 7;
        const float* xr = x + (size_t)(mgrp * 128 + r) * DIM;
        float ss = 0.f;
#pragma unroll
        for (int i = 0; i < 16; ++i) {
            const floatx4 vv = *(const floatx4*)(xr + ((q + (i << 3)) << 2));
            ss += vv[0]*vv[0] + vv[1]*vv[1] + vv[2]*vv[2] + vv[3]*vv[3];
        }
        ss += __shfl_xor(ss, 1);
        ss += __shfl_xor(ss, 2);
        ss += __shfl_xor(ss, 4);
        const float rn = 1.0f / fmaxf(sqrtf(ss), 1e-12f);
#pragma unroll
        for (int i = 0; i < 16; ++i) {
            const floatx4 vv = *(const floatx4*)(xr + ((q + (i << 3)) << 2));
            const int col4 = q + (i << 3);
            const int gp = (col4 >> 1) ^ (r & 7);
            ushort4 u;
            u.x = f2bf(vv[0]*rn); u.y = f2bf(vv[1]*rn);
            u.z = f2bf(vv[2]*rn); u.w = f2bf(vv[3]*rn);
            *(ushort4*)(&ash[r * DIM + gp * 8 + (col4 & 1) * 4]) = u;
            if (stream == 0)   // publish exact bf16 x-hat for reduce_lse
                *(ushort4*)(xn + (size_t)(mgrp * 128 + r) * DIM + col4 * 4) = u;
        }
    }
    ((float*)pacc)[t] = 0.f;   // zero 8x64
    __syncthreads();

    const int arow0 = (g * 64 + l31) * DIM;        // mf=0 rows
    const int arow1 = (g * 64 + 32 + l31) * DIM;   // mf=1 rows
    const float sa = S_SCALE * LOG2E;
    const float sb = -S_SCALE * LOG2E;

    for (int tile = stream; tile < NT; tile += NSTREAM) {
        const int cb0 = tile * BNB + np * 64;
        const bool vf0 = cb0 < NCLASS;             // 32-class frags never partial
        const bool vf1 = cb0 + 32 < NCLASS;
        const u16* wp0 = wnf + (size_t)min(cb0 >> 5, NCB - 1) * 16384 + lane * 8;
        const u16* wp1 = wnf + (size_t)min((cb0 >> 5) + 1, NCB - 1) * 16384 + lane * 8;

        floatx16 acc00 = (floatx16)0.0f, acc01 = (floatx16)0.0f;
        floatx16 acc10 = (floatx16)0.0f, acc11 = (floatx16)0.0f;

        // 4-slot named B pipeline; each load = 64 lanes x 16B contiguous (1 txn)
        short8 s0a = *(const short8*)(wp0 +    0), s0b = *(const short8*)(wp1 +    0);
        short8 s1a = *(const short8*)(wp0 +  512), s1b = *(const short8*)(wp1 +  512);
        short8 s2a = *(const short8*)(wp0 + 1024), s2b = *(const short8*)(wp1 + 1024);
        short8 s3a = *(const short8*)(wp0 + 1536), s3b = *(const short8*)(wp1 + 1536);

#pragma unroll
        for (int ks = 0; ks < 32; ks += 4) {
#define STEP(K, BA, BB)                                                          \
            {                                                                    \
                const int gb = ((((K) << 1) + hi) ^ swz) << 3;                   \
                const short8 a0 = *(const short8*)(&ash[arow0 + gb]);            \
                const short8 a1 = *(const short8*)(&ash[arow1 + gb]);            \
                acc00 = __builtin_amdgcn_mfma_f32_32x32x16_bf16(a0, BA, acc00, 0, 0, 0); \
                acc10 = __builtin_amdgcn_mfma_f32_32x32x16_bf16(a1, BA, acc10, 0, 0, 0); \
                acc01 = __builtin_amdgcn_mfma_f32_32x32x16_bf16(a0, BB, acc01, 0, 0, 0); \
                acc11 = __builtin_amdgcn_mfma_f32_32x32x16_bf16(a1, BB, acc11, 0, 0, 0); \
                if ((K) + 4 < 32) {                                              \
                    BA = *(const short8*)(wp0 + ((K) + 4) * 512);                 \
                    BB = *(const short8*)(wp1 + ((K) + 4) * 512);                 \
                }                                                                \
            }
            STEP(ks + 0, s0a, s0b)
            STEP(ks + 1, s1a, s1b)
            STEP(ks + 2, s2a, s2b)
            STEP(ks + 3, s3a, s3b)
#undef STEP
        }

        // ---- epilogue: exp accumulate into LDS running sums (wave-private) ----
        if (vf0 | vf1) {
#pragma unroll
            for (int r = 0; r < 16; ++r) {
                float p0 = vf0 ? exp2f(fmaf(acc00[r], sa, sb)) : 0.f;
                if (vf1) p0 += exp2f(fmaf(acc01[r], sa, sb));
                float p1 = vf0 ? exp2f(fmaf(acc10[r], sa, sb)) : 0.f;
                if (vf1) p1 += exp2f(fmaf(acc11[r], sa, sb));
                p0 += __shfl_xor(p0, 1);  p1 += __shfl_xor(p1, 1);
                p0 += __shfl_xor(p0, 2);  p1 += __shfl_xor(p1, 2);
                p0 += __shfl_xor(p0, 4);  p1 += __shfl_xor(p1, 4);
                p0 += __shfl_xor(p0, 8);  p1 += __shfl_xor(p1, 8);
                p0 += __shfl_xor(p0, 16); p1 += __shfl_xor(p1, 16);
                if (l31 == 0) {
                    const int row32 = (r & 3) + ((r >> 2) << 3) + (hi << 2);
                    pacc[wv][row32]      += p0;
                    pacc[wv][32 + row32] += p1;
                }
            }
        }
    }

    __syncthreads();
    if (t < 128) {
        const int g2 = t >> 6, i64 = t & 63;
        const float s = pacc[g2*4+0][i64] + pacc[g2*4+1][i64]
                      + pacc[g2*4+2][i64] + pacc[g2*4+3][i64];
        partials[(size_t)stream * BATCH + mgrp * 128 + t] = s;
    }
}

// ---------------- Kernel 2: LSE + exact target term + nll ----------------
__global__ void reduce_lse(const float* __restrict__ partials,
                           const u16* __restrict__ wnf,
                           const u16* __restrict__ xn,
                           const int* __restrict__ target,
                           float* __restrict__ nll) {
    const int m = blockIdx.x;
    const int t = threadIdx.x; // 64 = 1 wave
    float tot = partials[(size_t)t * BATCH + m];
#pragma unroll
    for (int d = 1; d < 64; d <<= 1) tot += __shfl_xor(tot, d);

    // thread t covers k = t*8..t*8+7 of the target row (fragment-major decode)
    const int tg = target[m];
    const u16* wrow = wnf + (size_t)(tg >> 5) * 16384
                    + (t >> 1) * 512 + ((t & 1) * 32 + (tg & 31)) * 8;
    const short8 wv8 = *(const short8*)(wrow);
    const short8 xv  = *(const short8*)(xn + (size_t)m * DIM + t * 8);
    float dot = 0.f;
#pragma unroll
    for (int j = 0; j < 8; ++j)
        dot += bf2f((u16)xv[j]) * bf2f((u16)wv8[j]);
#pragma unroll
    for (int d = 1; d < 64; d <<= 1) dot += __shfl_xor(dot, d);

    if (t == 0) {
        const float cosv = dot;                          // both unit bf16 vectors
        const float sine = sqrtf(fmaxf(1.f - cosv * cosv, 0.f));
        float phi = cosv * COSM - sine * SINM;
        if (!(cosv > 0.f)) phi = cosv;                   // easy_margin
        const float lgp = S_SCALE * phi, lgc = S_SCALE * cosv;
        // main loop summed the target col as a plain class: swap it for phi
        const float tt = tot - __expf(lgc - S_SCALE) + __expf(lgp - S_SCALE);
        nll[m] = (logf(fmaxf(tt, 1e-30f)) + S_SCALE) - lgp;
    }
}

// ---------------- Kernel 3: mean ----------------
__global__ void reduce_mean(const float* __restrict__ nll, float* __restrict__ out) {
    const int t = threadIdx.x; // 512
    float s = nll[t];
#pragma unroll
    for (int d = 1; d < 64; d <<= 1) s += __shfl_xor(s, d);
    __shared__ float red[8];
    if ((t & 63) == 0) red[t >> 6] = s;
    __syncthreads();
    if (t == 0) {
        float tot = 0.f;
#pragma unroll
        for (int i = 0; i < 8; ++i) tot += red[i];
        out[0] = tot / (float)BATCH;
    }
}

extern "C" void kernel_launch(void* const* d_in, const int* in_sizes, int n_in,
                              void* d_out, int out_size, void* d_ws, size_t ws_size,
                              hipStream_t stream) {
    const float* x = (const float*)d_in[0];
    const float* w = (const float*)d_in[1];
    const int* target = (const int*)d_in[2];

    char* ws = (char*)d_ws;
    u16* xn        = (u16*)ws;
    float* partials= (float*)(ws + 524288);
    float* nll     = (float*)(ws + 655360);
    u16* wnf       = (u16*)(ws + 657408);   // 102.4 MB fragment-major

    wnorm_kernel<<<NCB, 512, 0, stream>>>(w, wnf);
    arcface_main<<<GRID, 512, 0, stream>>>(x, wnf, xn, partials);
    reduce_lse<<<BATCH, 64, 0, stream>>>(partials, wnf, xn, target, nll);
    reduce_mean<<<1, 512, 0, stream>>>(nll, (float*)d_out);
}